// Round 2
// baseline (255.655 us; speedup 1.0000x reference)
//
#include <hip/hip_runtime.h>

// Problem constants (reference: M, B, D = 32, 64, 8192)
#define Mh 32
#define Bh 64
#define Dh 8192
#define KCH 1024          // K-range per gram workgroup
#define NCH (Dh / KCH)    // 8 chunks
#define STG 128           // k per LDS stage
#define NST (KCH / STG)   // 8 stages

// Workspace layout (float offsets). Total ~4.34 MB. No atomics -> no memset.
#define OFF_PSY 0                         // [8][64][1024] partial Wsy
#define OFF_PYY 524288                    // [8][64][1024] partial Wyy
#define OFF_PVS 1048576                   // [8][64][32]   partial s_i.frc
#define OFF_PVY (OFF_PVS + 16384)         // [8][64][32]   partial y_i.frc
#define OFF_CY  (OFF_PVY + 16384)         // [64][32]      g * a_i
#define OFF_CS  (OFF_CY + 2048)           // [64][32]      b_i - a_i
#define OFF_G   (OFF_CS + 2048)           // [64]          g

// ---------------------------------------------------------------------------
// Kernel A: batched Gram partials. grid = 64 b x 8 k-chunks, 256 threads.
// Software-pipelined: stage st+1's global loads are in flight during stage
// st's compute. XOR swizzle (col ^ ((row>>2)&7)) keeps LDS conflict-free.
// No atomics: per-chunk partials written with plain float4 stores.
// ---------------------------------------------------------------------------
__global__ __launch_bounds__(256) void gram_kernel(
    const float* __restrict__ s, const float* __restrict__ y,
    const float* __restrict__ frc, float* __restrict__ ws)
{
    __shared__ float sT[32 * STG];
    __shared__ float yT[32 * STG];
    __shared__ float fT[STG];

    const int b  = blockIdx.x & 63;
    const int ch = blockIdx.x >> 6;
    const int k0 = ch * KCH;
    const int t  = threadIdx.x;
    const int w  = t >> 6;
    const int l  = t & 63;
    const int tx = l & 7;
    const int ty = l >> 3;
    const size_t base = (size_t)b * Dh;

    float asy[4][4] = {};
    float ayy[4][4] = {};
    float avs[4] = {}, avy[4] = {};

    // staging map: 32 rows x 32 float4-cols; thread covers 4 (row,col) slots
    int ri[4], rc[4];
    #pragma unroll
    for (int rep = 0; rep < 4; ++rep) {
        const int idx = t + rep * 256;
        ri[rep] = idx >> 5;
        rc[rep] = idx & 31;
    }

    float4 pS[4], pY[4], pF;
    auto issue = [&](int kb) {
        #pragma unroll
        for (int rep = 0; rep < 4; ++rep) {
            const size_t off = ((size_t)ri[rep] * Bh) * Dh + base + kb + (rc[rep] << 2);
            pS[rep] = *(const float4*)(s + off);
            pY[rep] = *(const float4*)(y + off);
        }
        if (t < 32) pF = *(const float4*)(frc + base + kb + (t << 2));
    };

    issue(k0);
    for (int st = 0; st < NST; ++st) {
        __syncthreads();                  // prior stage's compute done
        #pragma unroll
        for (int rep = 0; rep < 4; ++rep) {
            const int col = rc[rep] ^ ((ri[rep] >> 2) & 7);
            *(float4*)&sT[ri[rep] * STG + (col << 2)] = pS[rep];
            *(float4*)&yT[ri[rep] * STG + (col << 2)] = pY[rep];
        }
        if (t < 32) *(float4*)&fT[t << 2] = pF;
        __syncthreads();
        if (st + 1 < NST) issue(k0 + (st + 1) * STG);  // prefetch next stage

        // wave w covers float4-cols [8w, 8w+8)
        #pragma unroll
        for (int kk = 0; kk < 8; ++kk) {
            const int c0 = (w << 3) + kk;
            float4 sv[4], tv[4], xv[4];
            #pragma unroll
            for (int aa = 0; aa < 4; ++aa) {
                sv[aa] = *(const float4*)&sT[((ty << 2) + aa) * STG + ((c0 ^ ty) << 2)];
                tv[aa] = *(const float4*)&yT[((ty << 2) + aa) * STG + ((c0 ^ ty) << 2)];
                xv[aa] = *(const float4*)&yT[((tx << 2) + aa) * STG + ((c0 ^ tx) << 2)];
            }
            const float4 fv = *(const float4*)&fT[c0 << 2];
            #pragma unroll
            for (int aa = 0; aa < 4; ++aa) {
                #pragma unroll
                for (int cc = 0; cc < 4; ++cc) {
                    asy[aa][cc] += sv[aa].x * xv[cc].x + sv[aa].y * xv[cc].y
                                 + sv[aa].z * xv[cc].z + sv[aa].w * xv[cc].w;
                    ayy[aa][cc] += tv[aa].x * xv[cc].x + tv[aa].y * xv[cc].y
                                 + tv[aa].z * xv[cc].z + tv[aa].w * xv[cc].w;
                }
                avs[aa] += sv[aa].x * fv.x + sv[aa].y * fv.y + sv[aa].z * fv.z + sv[aa].w * fv.w;
                avy[aa] += tv[aa].x * fv.x + tv[aa].y * fv.y + tv[aa].z * fv.z + tv[aa].w * fv.w;
            }
        }
    }

    // cross-wave reduction into sT (sy), yT (yy), fT (vs/vy)
    __syncthreads();
    for (int wv = 0; wv < 4; ++wv) {
        if (w == wv) {
            #pragma unroll
            for (int aa = 0; aa < 4; ++aa) {
                #pragma unroll
                for (int cc = 0; cc < 4; ++cc) {
                    const int e = ((ty << 2) + aa) * 32 + (tx << 2) + cc;
                    if (wv == 0) { sT[e] = asy[aa][cc];  yT[e] = ayy[aa][cc]; }
                    else         { sT[e] += asy[aa][cc]; yT[e] += ayy[aa][cc]; }
                }
                if (tx == 0) {
                    const int i = (ty << 2) + aa;
                    if (wv == 0) { fT[i] = avs[aa];  fT[32 + i] = avy[aa]; }
                    else         { fT[i] += avs[aa]; fT[32 + i] += avy[aa]; }
                }
            }
        }
        __syncthreads();
    }

    // plain partial writes (no atomics)
    float* PSY = ws + OFF_PSY + ((size_t)ch * Bh + b) * 1024;
    float* PYY = ws + OFF_PYY + ((size_t)ch * Bh + b) * 1024;
    *(float4*)&PSY[t << 2] = *(const float4*)&sT[t << 2];
    *(float4*)&PYY[t << 2] = *(const float4*)&yT[t << 2];
    if (t < 32)      ws[OFF_PVS + (ch * 64 + b) * 32 + t] = fT[t];
    else if (t < 64) ws[OFF_PVY + (ch * 64 + b) * 32 + (t - 32)] = fT[t];   // fT[32+(t-32)]
}

// ---------------------------------------------------------------------------
// Kernel B: reduce 8 partials, then the M=32 f64 recursion (wave 0).
// One block (256 threads) per b.
// ---------------------------------------------------------------------------
__global__ __launch_bounds__(256) void recur_kernel(float* __restrict__ ws)
{
    __shared__ float WSY[1024], WYY[1024], VS[32], VY[32];
    const int b = blockIdx.x;
    const int t = threadIdx.x;

    float4 a4 = make_float4(0.f, 0.f, 0.f, 0.f);
    float4 c4 = make_float4(0.f, 0.f, 0.f, 0.f);
    #pragma unroll
    for (int ch = 0; ch < NCH; ++ch) {
        const float4 u = *(const float4*)&ws[OFF_PSY + ((size_t)ch * Bh + b) * 1024 + (t << 2)];
        const float4 v = *(const float4*)&ws[OFF_PYY + ((size_t)ch * Bh + b) * 1024 + (t << 2)];
        a4.x += u.x; a4.y += u.y; a4.z += u.z; a4.w += u.w;
        c4.x += v.x; c4.y += v.y; c4.z += v.z; c4.w += v.w;
    }
    *(float4*)&WSY[t << 2] = a4;
    *(float4*)&WYY[t << 2] = c4;
    if (t < 32) {
        float av = 0.f, cv = 0.f;
        #pragma unroll
        for (int ch = 0; ch < NCH; ++ch) {
            av += ws[OFF_PVS + (ch * 64 + b) * 32 + t];
            cv += ws[OFF_PVY + (ch * 64 + b) * 32 + t];
        }
        VS[t] = av; VY[t] = cv;
    }
    __syncthreads();
    if (t >= 64) return;

    const int i = t & 31;
    float row_sy[32], col_sy[32], row_yy[32];
    #pragma unroll
    for (int j = 0; j < 32; ++j) {
        row_sy[j] = WSY[i * 32 + j];
        col_sy[j] = WSY[j * 32 + i];
        row_yy[j] = WYY[i * 32 + j];
    }

    const double r = 1.0 / (double)row_sy[i];
    double acc = -(double)VS[i];
    double a_val = 0.0;
    #pragma unroll
    for (int j = 31; j >= 0; --j) {
        const double aj = __shfl(r, j) * __shfl(acc, j);
        if (i == j) a_val = aj;
        if (i < j)  acc -= aj * (double)row_sy[j];
    }

    const double g = (double)WSY[31 * 32 + 31] / (double)WYY[31 * 32 + 31];

    double u = -(double)VY[i];
    #pragma unroll
    for (int j = 0; j < 32; ++j)
        u -= __shfl(a_val, j) * (double)row_yy[j];
    u *= g;

    double tt = u;
    double b_val = 0.0;
    #pragma unroll
    for (int j = 0; j < 32; ++j) {
        const double bj = __shfl(r, j) * __shfl(tt, j);
        if (i == j) b_val = bj;
        const double dj = __shfl(a_val, j) - bj;
        if (i > j) tt += dj * (double)col_sy[j];
    }

    if (t < 32) {
        ws[OFF_CY + b * 32 + i] = (float)(g * a_val);
        ws[OFF_CS + b * 32 + i] = (float)(b_val - a_val);
    }
    if (t == 0) ws[OFF_G + b] = (float)g;
}

// ---------------------------------------------------------------------------
// Kernel C: out[b,d] = g*frc + sum_i cy[i]*y[i,b,d] + cs[i]*s[i,b,d]
// 512 blocks x 256 threads, 1 float4/thread; loads batched 16-deep for MLP.
// ---------------------------------------------------------------------------
__global__ __launch_bounds__(256) void combine_kernel(
    const float* __restrict__ s, const float* __restrict__ y,
    const float* __restrict__ frc, const float* __restrict__ ws,
    float* __restrict__ out)
{
    __shared__ float cy[32], cs[32];
    const int b  = blockIdx.x & 63;
    const int ch = blockIdx.x >> 6;
    const int t  = threadIdx.x;
    if (t < 32) { cy[t] = ws[OFF_CY + b * 32 + t]; cs[t] = ws[OFF_CS + b * 32 + t]; }
    __syncthreads();

    const int d = ch * 1024 + (t << 2);
    const size_t base = (size_t)b * Dh + d;
    const float g = ws[OFF_G + b];
    const float4 fv = *(const float4*)(frc + base);
    float4 acc;
    acc.x = g * fv.x; acc.y = g * fv.y; acc.z = g * fv.z; acc.w = g * fv.w;

    const float* py = y + base;
    const float* ps = s + base;
    #pragma unroll
    for (int grp = 0; grp < 4; ++grp) {
        float4 yv[8], sv[8];
        #pragma unroll
        for (int j = 0; j < 8; ++j) {
            const size_t off = (size_t)(grp * 8 + j) * ((size_t)Bh * Dh);
            yv[j] = *(const float4*)(py + off);
            sv[j] = *(const float4*)(ps + off);
        }
        #pragma unroll
        for (int j = 0; j < 8; ++j) {
            const float a1 = cy[grp * 8 + j], a2 = cs[grp * 8 + j];
            acc.x += a1 * yv[j].x + a2 * sv[j].x;
            acc.y += a1 * yv[j].y + a2 * sv[j].y;
            acc.z += a1 * yv[j].z + a2 * sv[j].z;
            acc.w += a1 * yv[j].w + a2 * sv[j].w;
        }
    }
    *(float4*)(out + base) = acc;
}

extern "C" void kernel_launch(void* const* d_in, const int* in_sizes, int n_in,
                              void* d_out, int out_size, void* d_ws, size_t ws_size,
                              hipStream_t stream)
{
    const float* s   = (const float*)d_in[0];
    const float* y   = (const float*)d_in[1];
    const float* frc = (const float*)d_in[2];
    float* out = (float*)d_out;
    float* ws  = (float*)d_ws;

    gram_kernel<<<dim3(Bh * NCH), dim3(256), 0, stream>>>(s, y, frc, ws);
    recur_kernel<<<dim3(Bh), dim3(256), 0, stream>>>(ws);
    combine_kernel<<<dim3(Bh * NCH), dim3(256), 0, stream>>>(s, y, frc, ws, out);
}